// Round 2
// baseline (359.921 us; speedup 1.0000x reference)
//
#include <hip/hip_runtime.h>
#include <math.h>

// GE2E loss on MI355X.
// out = sum_k counts[k]*lse[k] - sum_i logit_self[i]
// lse[k] = log sum_j exp(S[j,k]); S capped at w*1+b=5 -> no max-subtraction needed.

__device__ inline float waveReduceSum(float v) {
#pragma unroll
    for (int m = 32; m >= 1; m >>= 1) v += __shfl_xor(v, m, 64);
    return v;
}

// --- K1: per-row inverse norm + class counts ---
__global__ void k_norms(const float* __restrict__ emb, const int* __restrict__ y,
                        float* __restrict__ inv_norm, int* __restrict__ counts,
                        int N, int D) {
    int wid = threadIdx.x >> 6;
    int lane = threadIdx.x & 63;
    int row = blockIdx.x * 4 + wid;
    if (row >= N) return;
    const float4* p = reinterpret_cast<const float4*>(emb + (size_t)row * D);
    float s = 0.f;
    for (int c = lane; c * 4 < D; c += 64) {
        float4 v = p[c];
        s += v.x * v.x + v.y * v.y + v.z * v.z + v.w * v.w;
    }
    s = waveReduceSum(s);
    if (lane == 0) {
        inv_norm[row] = 1.0f / fmaxf(sqrtf(s), 1e-12f);
        atomicAdd(&counts[y[row]], 1);
    }
}

// --- K2: exclusive scan of counts (C=256, trivial) ---
__global__ void k_scan(const int* __restrict__ counts, int* __restrict__ offsets, int C) {
    if (threadIdx.x == 0 && blockIdx.x == 0) {
        int acc = 0;
        for (int c = 0; c < C; ++c) { offsets[c] = acc; acc += counts[c]; }
    }
}

// --- K3: scatter member lists ---
__global__ void k_scatter(const int* __restrict__ y, const int* __restrict__ offsets,
                          int* __restrict__ cursor, int* __restrict__ members, int N) {
    int i = blockIdx.x * 256 + threadIdx.x;
    if (i < N) {
        int c = y[i];
        int pos = atomicAdd(&cursor[c], 1);
        members[offsets[c] + pos] = i;
    }
}

// --- K4: per-class sums of normalized rows (block per class) ---
__global__ void k_centroid(const float* __restrict__ emb, const float* __restrict__ inv_norm,
                           const int* __restrict__ members, const int* __restrict__ offsets,
                           const int* __restrict__ counts, float* __restrict__ csum, int D) {
    __shared__ float lds[4 * 512];   // 4 wave partials, D<=512
    int c = blockIdx.x;
    int wid = threadIdx.x >> 6, lane = threadIdx.x & 63;
    int cnt = counts[c], off = offsets[c];
    int nch = D / 256;               // float4 chunks per lane (D=512 -> 2)
    float4 acc[2];
    acc[0] = make_float4(0, 0, 0, 0); acc[1] = make_float4(0, 0, 0, 0);
    for (int m = wid; m < cnt; m += 4) {
        int row = members[off + m];
        float inv = inv_norm[row];
        const float4* p = reinterpret_cast<const float4*>(emb + (size_t)row * D);
        for (int ch = 0; ch < nch; ++ch) {
            float4 v = p[ch * 64 + lane];
            acc[ch].x += v.x * inv; acc[ch].y += v.y * inv;
            acc[ch].z += v.z * inv; acc[ch].w += v.w * inv;
        }
    }
    for (int ch = 0; ch < nch; ++ch)
        reinterpret_cast<float4*>(lds)[wid * 128 + ch * 64 + lane] = acc[ch];
    __syncthreads();
    for (int d = threadIdx.x; d < D; d += blockDim.x) {
        float s = lds[d] + lds[512 + d] + lds[1024 + d] + lds[1536 + d];
        csum[(size_t)c * D + d] = s;
    }
}

// --- K5: per-class column scale = w / (cnt * max(cen_norm,1e-8)) ---
__global__ void k_colscale(const float* __restrict__ csum, const int* __restrict__ counts,
                           const float* __restrict__ wptr, float* __restrict__ colscale,
                           int C, int D) {
    int wid = threadIdx.x >> 6, lane = threadIdx.x & 63;
    int c = blockIdx.x * 4 + wid;
    if (c >= C) return;
    const float4* p = reinterpret_cast<const float4*>(csum + (size_t)c * D);
    float s = 0.f;
    for (int i = lane; i * 4 < D; i += 64) {
        float4 v = p[i];
        s += v.x * v.x + v.y * v.y + v.z * v.z + v.w * v.w;
    }
    s = waveReduceSum(s);
    if (lane == 0) {
        float cnt = (float)counts[c];
        float cen_norm = sqrtf(s) / cnt;
        colscale[c] = wptr[0] / (cnt * fmaxf(cen_norm, 1e-8f));
    }
}

// --- K6: self-similarity logits (wave per row) ---
__global__ void k_selfsim(const float* __restrict__ emb, const int* __restrict__ y,
                          const float* __restrict__ inv_norm, const float* __restrict__ csum,
                          const int* __restrict__ counts, const float* __restrict__ wptr,
                          const float* __restrict__ bptr, float* __restrict__ logit_self,
                          int N, int D) {
    int wid = threadIdx.x >> 6, lane = threadIdx.x & 63;
    int row = blockIdx.x * 4 + wid;
    if (row >= N) return;
    int c = y[row];
    float inv = inv_norm[row];
    const float4* pe = reinterpret_cast<const float4*>(emb + (size_t)row * D);
    const float4* pc = reinterpret_cast<const float4*>(csum + (size_t)c * D);
    float dot = 0.f, un = 0.f;
    for (int i = lane; i * 4 < D; i += 64) {
        float4 e4 = pe[i]; float4 s4 = pc[i];
        float ex = e4.x * inv, ey = e4.y * inv, ez = e4.z * inv, ew = e4.w * inv;
        float ux = s4.x - ex, uy = s4.y - ey, uz = s4.z - ez, uw = s4.w - ew;
        dot += ex * ux + ey * uy + ez * uz + ew * uw;
        un  += ux * ux + uy * uy + uz * uz + uw * uw;
    }
    dot = waveReduceSum(dot);
    un  = waveReduceSum(un);
    if (lane == 0) {
        float cm1 = (float)(counts[c] - 1);
        float denom = fmaxf(sqrtf(un), cm1 * 1e-8f);
        logit_self[row] = wptr[0] * (dot / denom) + bptr[0];
    }
}

// --- K7: tiled fp32 GEMM (e @ csum^T) fused with exp + per-column partial sums ---
#define BM 64
#define BN 64
#define BK 32
#define LDP 36   // padded leading dim (float4-aligned)

__global__ __launch_bounds__(256) void k_gemm_colsum(
        const float* __restrict__ emb, const float* __restrict__ inv_norm,
        const float* __restrict__ csum, const int* __restrict__ y,
        const float* __restrict__ colscale, const float* __restrict__ bptr,
        const float* __restrict__ logit_self, float* __restrict__ colpart,
        int N, int D, int C) {
    __shared__ float As[BM * LDP];
    __shared__ float Bs[BN * LDP];
    int tid = threadIdx.x;
    int tx = tid & 15, ty = tid >> 4;
    int r0 = blockIdx.x * BM, c0 = blockIdx.y * BN;
    float acc[4][4] = {};
    int nk = D / BK;
    for (int kt = 0; kt < nk; ++kt) {
#pragma unroll
        for (int l = 0; l < 2; ++l) {
            int idx = tid + l * 256;     // 0..511 float4 slots
            int row = idx >> 3;          // 8 float4 per row (32 floats)
            int k4 = idx & 7;
            float inv = inv_norm[r0 + row];
            float4 v = *reinterpret_cast<const float4*>(
                emb + (size_t)(r0 + row) * D + kt * BK + k4 * 4);
            *reinterpret_cast<float4*>(&As[row * LDP + k4 * 4]) =
                make_float4(v.x * inv, v.y * inv, v.z * inv, v.w * inv);
            float4 u = *reinterpret_cast<const float4*>(
                csum + (size_t)(c0 + row) * D + kt * BK + k4 * 4);
            *reinterpret_cast<float4*>(&Bs[row * LDP + k4 * 4]) = u;
        }
        __syncthreads();
#pragma unroll
        for (int kk = 0; kk < BK; ++kk) {
            float a[4], bq[4];
#pragma unroll
            for (int i = 0; i < 4; ++i) a[i] = As[(ty * 4 + i) * LDP + kk];
#pragma unroll
            for (int j = 0; j < 4; ++j) bq[j] = Bs[(tx * 4 + j) * LDP + kk];
#pragma unroll
            for (int i = 0; i < 4; ++i)
#pragma unroll
                for (int j = 0; j < 4; ++j)
                    acc[i][j] += a[i] * bq[j];
        }
        __syncthreads();
    }
    // epilogue: logits -> exp -> per-column partial sums
    float bv = bptr[0];
    float cs[4]; int cls[4];
#pragma unroll
    for (int j = 0; j < 4; ++j) { cls[j] = c0 + tx * 4 + j; cs[j] = colscale[cls[j]]; }
    float colacc[4] = {0, 0, 0, 0};
#pragma unroll
    for (int i = 0; i < 4; ++i) {
        int row = r0 + ty * 4 + i;
        int yc = y[row];
        float lself = logit_self[row];
#pragma unroll
        for (int j = 0; j < 4; ++j) {
            float logit = acc[i][j] * cs[j] + bv;
            if (yc == cls[j]) logit = lself;   // own-class substitution
            colacc[j] += expf(logit);
        }
    }
    // reduce the 16 ty-groups per column (reuse As; all LDS reads finished pre-sync)
    float* red = As;
#pragma unroll
    for (int j = 0; j < 4; ++j) red[ty * 64 + tx * 4 + j] = colacc[j];
    __syncthreads();
    if (tid < 64) {
        float s = 0.f;
#pragma unroll
        for (int g = 0; g < 16; ++g) s += red[g * 64 + tid];
        colpart[(size_t)blockIdx.x * C + c0 + tid] = s;
    }
}

// --- K8: finalize: lse per column, weighted sum, minus self-logit sum ---
__global__ void k_final(const float* __restrict__ colpart, const int* __restrict__ counts,
                        const float* __restrict__ logit_self, float* __restrict__ out,
                        int N, int C, int rowTiles) {
    __shared__ float lds[256];
    int tid = threadIdx.x;
    float selfs = 0.f;
    for (int i = tid; i < N; i += 256) selfs += logit_self[i];
    float contrib = 0.f;
    for (int k = tid; k < C; k += 256) {
        float s = 0.f;
        for (int t = 0; t < rowTiles; ++t) s += colpart[(size_t)t * C + k];
        contrib += (float)counts[k] * logf(s);
    }
    lds[tid] = contrib - selfs;
    __syncthreads();
    for (int off = 128; off >= 1; off >>= 1) {
        if (tid < off) lds[tid] += lds[tid + off];
        __syncthreads();
    }
    if (tid == 0) out[0] = lds[0];
}

extern "C" void kernel_launch(void* const* d_in, const int* in_sizes, int n_in,
                              void* d_out, int out_size, void* d_ws, size_t ws_size,
                              hipStream_t stream) {
    const float* emb  = (const float*)d_in[0];
    const int*   y    = (const int*)d_in[1];
    const float* wptr = (const float*)d_in[2];
    const float* bptr = (const float*)d_in[3];
    float* out = (float*)d_out;
    int N = in_sizes[1];
    int D = in_sizes[0] / N;
    const int C = 256;
    int rowTiles = N / BM;

    float* ws = (float*)d_ws;
    float* csum       = ws;                                   // C*D
    float* colpart    = csum + (size_t)C * D;                 // rowTiles*C
    int*   counts     = (int*)(colpart + (size_t)rowTiles * C); // C
    int*   cursor     = counts + C;                           // C
    int*   offsets    = cursor + C;                           // C
    float* inv_norm   = (float*)(offsets + C);                // N
    float* logit_self = inv_norm + N;                         // N
    int*   members    = (int*)(logit_self + N);               // N
    float* colscale   = (float*)(members + N);                // C

    // zero the accumulated regions: csum, colpart, counts, cursor
    size_t zero_bytes = ((size_t)C * D + (size_t)rowTiles * C + 2 * C) * sizeof(float);
    (void)hipMemsetAsync(ws, 0, zero_bytes, stream);

    k_norms  <<<(N + 3) / 4, 256, 0, stream>>>(emb, y, inv_norm, counts, N, D);
    k_scan   <<<1, 64, 0, stream>>>(counts, offsets, C);
    k_scatter<<<(N + 255) / 256, 256, 0, stream>>>(y, offsets, cursor, members, N);
    k_centroid<<<C, 256, 0, stream>>>(emb, inv_norm, members, offsets, counts, csum, D);
    k_colscale<<<(C + 3) / 4, 256, 0, stream>>>(csum, counts, wptr, colscale, C, D);
    k_selfsim<<<(N + 3) / 4, 256, 0, stream>>>(emb, y, inv_norm, csum, counts, wptr, bptr,
                                               logit_self, N, D);
    dim3 grid(N / BM, C / BN);
    k_gemm_colsum<<<grid, 256, 0, stream>>>(emb, inv_norm, csum, y, colscale, bptr,
                                            logit_self, colpart, N, D, C);
    k_final<<<1, 256, 0, stream>>>(colpart, counts, logit_self, out, N, C, rowTiles);
}

// Round 3
// 183.579 us; speedup vs baseline: 1.9606x; 1.9606x over previous
//
#include <hip/hip_runtime.h>
#include <math.h>

// GE2E loss on MI355X.
// out = sum_k counts[k]*lse[k] - sum_i logit_self[i]
// lse[k] = log sum_j exp(S[j,k]); S capped at w*1+b=5 -> no max-subtraction needed.
// logit_self computed inside the GEMM epilogue from dot_own = e_i . csum_{y_i}:
//   u = csum_y - e_i ; dot(e,u) = dot_own - 1 ; |u|^2 = |csum_y|^2 - 2 dot_own + 1.

__device__ inline float waveReduceSum(float v) {
#pragma unroll
    for (int m = 32; m >= 1; m >>= 1) v += __shfl_xor(v, m, 64);
    return v;
}

// --- K1: per-row inverse norm + class counts ---
__global__ void k_norms(const float* __restrict__ emb, const int* __restrict__ y,
                        float* __restrict__ inv_norm, int* __restrict__ counts,
                        int N, int D) {
    int wid = threadIdx.x >> 6;
    int lane = threadIdx.x & 63;
    int row = blockIdx.x * 4 + wid;
    if (row >= N) return;
    const float4* p = reinterpret_cast<const float4*>(emb + (size_t)row * D);
    float s = 0.f;
    for (int c = lane; c * 4 < D; c += 64) {
        float4 v = p[c];
        s += v.x * v.x + v.y * v.y + v.z * v.z + v.w * v.w;
    }
    s = waveReduceSum(s);
    if (lane == 0) {
        inv_norm[row] = 1.0f / fmaxf(sqrtf(s), 1e-12f);
        atomicAdd(&counts[y[row]], 1);
    }
}

// --- K2: exclusive scan of counts (256-thread Hillis-Steele) ---
__global__ void k_scan(const int* __restrict__ counts, int* __restrict__ offsets, int C) {
    __shared__ int sc[256];
    int tid = threadIdx.x;
    int v = (tid < C) ? counts[tid] : 0;
    sc[tid] = v;
    __syncthreads();
    for (int off = 1; off < 256; off <<= 1) {
        int t = (tid >= off) ? sc[tid - off] : 0;
        __syncthreads();
        sc[tid] += t;
        __syncthreads();
    }
    if (tid < C) offsets[tid] = sc[tid] - v;
}

// --- K3: scatter member lists ---
__global__ void k_scatter(const int* __restrict__ y, const int* __restrict__ offsets,
                          int* __restrict__ cursor, int* __restrict__ members, int N) {
    int i = blockIdx.x * 256 + threadIdx.x;
    if (i < N) {
        int c = y[i];
        int pos = atomicAdd(&cursor[c], 1);
        members[offsets[c] + pos] = i;
    }
}

// --- K4: per-class sums of normalized rows (block per class) ---
__global__ void k_centroid(const float* __restrict__ emb, const float* __restrict__ inv_norm,
                           const int* __restrict__ members, const int* __restrict__ offsets,
                           const int* __restrict__ counts, float* __restrict__ csum, int D) {
    __shared__ float lds[4 * 512];
    int c = blockIdx.x;
    int wid = threadIdx.x >> 6, lane = threadIdx.x & 63;
    int cnt = counts[c], off = offsets[c];
    int nch = D / 256;
    float4 acc[2];
    acc[0] = make_float4(0, 0, 0, 0); acc[1] = make_float4(0, 0, 0, 0);
    for (int m = wid; m < cnt; m += 4) {
        int row = members[off + m];
        float inv = inv_norm[row];
        const float4* p = reinterpret_cast<const float4*>(emb + (size_t)row * D);
        for (int ch = 0; ch < nch; ++ch) {
            float4 v = p[ch * 64 + lane];
            acc[ch].x += v.x * inv; acc[ch].y += v.y * inv;
            acc[ch].z += v.z * inv; acc[ch].w += v.w * inv;
        }
    }
    for (int ch = 0; ch < nch; ++ch)
        reinterpret_cast<float4*>(lds)[wid * 128 + ch * 64 + lane] = acc[ch];
    __syncthreads();
    for (int d = threadIdx.x; d < D; d += blockDim.x) {
        float s = lds[d] + lds[512 + d] + lds[1024 + d] + lds[1536 + d];
        csum[(size_t)c * D + d] = s;
    }
}

// --- K5: per-class column scale + squared centroid-sum norm ---
__global__ void k_colscale(const float* __restrict__ csum, const int* __restrict__ counts,
                           const float* __restrict__ wptr, float* __restrict__ colscale,
                           float* __restrict__ normsq, int C, int D) {
    int wid = threadIdx.x >> 6, lane = threadIdx.x & 63;
    int c = blockIdx.x * 4 + wid;
    if (c >= C) return;
    const float4* p = reinterpret_cast<const float4*>(csum + (size_t)c * D);
    float s = 0.f;
    for (int i = lane; i * 4 < D; i += 64) {
        float4 v = p[i];
        s += v.x * v.x + v.y * v.y + v.z * v.z + v.w * v.w;
    }
    s = waveReduceSum(s);
    if (lane == 0) {
        normsq[c] = s;
        float cnt = (float)counts[c];
        float cen_norm = sqrtf(s) / cnt;
        colscale[c] = wptr[0] / (cnt * fmaxf(cen_norm, 1e-8f));
    }
}

// --- K6: GEMM (e @ csum^T) fused with self-logit + exp + per-column partial sums ---
// Tiles: BM=128 rows, BN=64 cols, BK=32. 256 threads, 8x4 acc per thread.
// LDS k-major with +4 pad: conflict-free ds_read_b128 fragments.
#define BM 128
#define BN 64
#define BK 32
#define LDA 132
#define LDB 68

__global__ __launch_bounds__(256) void k_gemm(
        const float* __restrict__ emb, const float* __restrict__ inv_norm,
        const float* __restrict__ csum, const int* __restrict__ y,
        const float* __restrict__ colscale, const float* __restrict__ normsq,
        const int* __restrict__ counts,
        const float* __restrict__ wptr, const float* __restrict__ bptr,
        float* __restrict__ logit_self, float* __restrict__ colpart,
        int N, int D, int C) {
    __shared__ float As[BK * LDA];   // 16.5 KB
    __shared__ float Bs[BK * LDB];   // 8.5 KB
    int tid = threadIdx.x;
    int tx = tid & 15, ty = tid >> 4;
    int r0 = blockIdx.x * BM, c0 = blockIdx.y * BN;
    int k4 = tid & 7;                // same for all staging slots of this thread

    int arow[4]; float ainv[4];
#pragma unroll
    for (int l = 0; l < 4; ++l) {
        arow[l] = (tid + l * 256) >> 3;       // 0..127
        ainv[l] = inv_norm[r0 + arow[l]];
    }
    int brow[2];
#pragma unroll
    for (int l = 0; l < 2; ++l) brow[l] = (tid + l * 256) >> 3;  // 0..63

    float acc[8][4] = {};
    int nk = D / BK;
    for (int kt = 0; kt < nk; ++kt) {
#pragma unroll
        for (int l = 0; l < 4; ++l) {
            float4 v = *reinterpret_cast<const float4*>(
                emb + (size_t)(r0 + arow[l]) * D + kt * BK + k4 * 4);
            float inv = ainv[l];
            As[(k4 * 4 + 0) * LDA + arow[l]] = v.x * inv;
            As[(k4 * 4 + 1) * LDA + arow[l]] = v.y * inv;
            As[(k4 * 4 + 2) * LDA + arow[l]] = v.z * inv;
            As[(k4 * 4 + 3) * LDA + arow[l]] = v.w * inv;
        }
#pragma unroll
        for (int l = 0; l < 2; ++l) {
            float4 u = *reinterpret_cast<const float4*>(
                csum + (size_t)(c0 + brow[l]) * D + kt * BK + k4 * 4);
            Bs[(k4 * 4 + 0) * LDB + brow[l]] = u.x;
            Bs[(k4 * 4 + 1) * LDB + brow[l]] = u.y;
            Bs[(k4 * 4 + 2) * LDB + brow[l]] = u.z;
            Bs[(k4 * 4 + 3) * LDB + brow[l]] = u.w;
        }
        __syncthreads();
#pragma unroll
        for (int kk = 0; kk < BK; ++kk) {
            float4 a0 = *reinterpret_cast<const float4*>(&As[kk * LDA + ty * 8]);
            float4 a1 = *reinterpret_cast<const float4*>(&As[kk * LDA + ty * 8 + 4]);
            float4 b0 = *reinterpret_cast<const float4*>(&Bs[kk * LDB + tx * 4]);
            float a[8] = {a0.x, a0.y, a0.z, a0.w, a1.x, a1.y, a1.z, a1.w};
            float bq[4] = {b0.x, b0.y, b0.z, b0.w};
#pragma unroll
            for (int i = 0; i < 8; ++i)
#pragma unroll
                for (int j = 0; j < 4; ++j)
                    acc[i][j] += a[i] * bq[j];
        }
        __syncthreads();
    }

    // epilogue: logits -> exp -> per-column partials; own-column -> self logit
    float bv = bptr[0], wv = wptr[0];
    int cls[4]; float cs4[4], nsq4[4], cm1[4];
#pragma unroll
    for (int j = 0; j < 4; ++j) {
        int c = c0 + tx * 4 + j;
        cls[j] = c;
        cs4[j] = colscale[c];
        nsq4[j] = normsq[c];
        cm1[j] = (float)(counts[c] - 1);
    }
    float colacc[4] = {0, 0, 0, 0};
#pragma unroll
    for (int i = 0; i < 8; ++i) {
        int row = r0 + ty * 8 + i;
        int yc = y[row];
#pragma unroll
        for (int j = 0; j < 4; ++j) {
            float dot = acc[i][j];
            float logit;
            if (yc == cls[j]) {
                float un2 = fmaxf(nsq4[j] - 2.f * dot + 1.f, 0.f);
                float denom = fmaxf(sqrtf(un2), cm1[j] * 1e-8f);
                logit = wv * (dot - 1.f) / denom + bv;
                logit_self[row] = logit;   // exactly one block/thread owns (row, y[row])
            } else {
                logit = dot * cs4[j] + bv;
            }
            colacc[j] += __expf(logit);
        }
    }
    // reduce 16 ty-groups per column (reuse As; trailing __syncthreads of k-loop protects)
    float* red = As;
#pragma unroll
    for (int j = 0; j < 4; ++j) red[ty * 64 + tx * 4 + j] = colacc[j];
    __syncthreads();
    if (tid < 64) {
        float s = 0.f;
#pragma unroll
        for (int g = 0; g < 16; ++g) s += red[g * 64 + tid];
        colpart[(size_t)blockIdx.x * C + c0 + tid] = s;
    }
}

// --- K7: finalize ---
__global__ void k_final(const float* __restrict__ colpart, const int* __restrict__ counts,
                        const float* __restrict__ logit_self, float* __restrict__ out,
                        int N, int C, int rowTiles) {
    __shared__ float lds[256];
    int tid = threadIdx.x;
    float selfs = 0.f;
    for (int i = tid; i < N; i += 256) selfs += logit_self[i];
    float contrib = 0.f;
    if (tid < C) {
        float s = 0.f;
        for (int t = 0; t < rowTiles; ++t) s += colpart[(size_t)t * C + tid];
        contrib = (float)counts[tid] * logf(s);
    }
    lds[tid] = contrib - selfs;
    __syncthreads();
    for (int off = 128; off >= 1; off >>= 1) {
        if (tid < off) lds[tid] += lds[tid + off];
        __syncthreads();
    }
    if (tid == 0) out[0] = lds[0];
}

extern "C" void kernel_launch(void* const* d_in, const int* in_sizes, int n_in,
                              void* d_out, int out_size, void* d_ws, size_t ws_size,
                              hipStream_t stream) {
    const float* emb  = (const float*)d_in[0];
    const int*   y    = (const int*)d_in[1];
    const float* wptr = (const float*)d_in[2];
    const float* bptr = (const float*)d_in[3];
    float* out = (float*)d_out;
    int N = in_sizes[1];
    int D = in_sizes[0] / N;
    const int C = 256;
    int rowTiles = N / BM;

    float* ws = (float*)d_ws;
    float* csum       = ws;                                     // C*D
    int*   counts     = (int*)(csum + (size_t)C * D);           // C
    int*   cursor     = counts + C;                             // C
    int*   offsets    = cursor + C;                             // C
    float* inv_norm   = (float*)(offsets + C);                  // N
    float* logit_self = inv_norm + N;                           // N
    int*   members    = (int*)(logit_self + N);                 // N
    float* colscale   = (float*)(members + N);                  // C
    float* normsq     = colscale + C;                           // C
    float* colpart    = normsq + C;                             // rowTiles*C

    // zero csum + counts + cursor (contiguous at the front)
    size_t zero_bytes = ((size_t)C * D + 2 * C) * sizeof(float);
    (void)hipMemsetAsync(ws, 0, zero_bytes, stream);

    k_norms   <<<(N + 3) / 4, 256, 0, stream>>>(emb, y, inv_norm, counts, N, D);
    k_scan    <<<1, 256, 0, stream>>>(counts, offsets, C);
    k_scatter <<<(N + 255) / 256, 256, 0, stream>>>(y, offsets, cursor, members, N);
    k_centroid<<<C, 256, 0, stream>>>(emb, inv_norm, members, offsets, counts, csum, D);
    k_colscale<<<(C + 3) / 4, 256, 0, stream>>>(csum, counts, wptr, colscale, normsq, C, D);
    dim3 grid(N / BM, C / BN);
    k_gemm    <<<grid, 256, 0, stream>>>(emb, inv_norm, csum, y, colscale, normsq, counts,
                                         wptr, bptr, logit_self, colpart, N, D, C);
    k_final   <<<1, 256, 0, stream>>>(colpart, counts, logit_self, out, N, C, rowTiles);
}

// Round 4
// 78.882 us; speedup vs baseline: 4.5628x; 2.3272x over previous
//
#include <hip/hip_runtime.h>
#include <math.h>
#include <stdint.h>

// GE2E loss on MI355X, bf16-MFMA GEMM core.
// out = sum_k counts[k]*log(sum_j exp(S[j,k])) - sum_i logit_self[i]
// Logits <= w*1+b = 5 -> exp without max-subtraction is safe in fp32.

typedef __attribute__((ext_vector_type(8))) short bf16x8;
typedef __attribute__((ext_vector_type(4))) float f32x4;
struct alignas(16) BF8 { unsigned short u[8]; };

__device__ inline float waveReduceSum(float v) {
#pragma unroll
    for (int m = 32; m >= 1; m >>= 1) v += __shfl_xor(v, m, 64);
    return v;
}

__device__ inline unsigned short f2bf(float f) {
    uint32_t u = __float_as_uint(f);
    return (unsigned short)((u + 0x7FFFu + ((u >> 16) & 1u)) >> 16);
}

__device__ inline void gload_lds16(const void* g, void* l) {
    __builtin_amdgcn_global_load_lds(
        (const __attribute__((address_space(1))) uint32_t*)g,
        (__attribute__((address_space(3))) uint32_t*)l, 16, 0, 0);
}

// --- K1: per-row inverse norm + class counts ---
__global__ void k_norms(const float* __restrict__ emb, const int* __restrict__ y,
                        float* __restrict__ inv_norm, int* __restrict__ counts,
                        int N, int D) {
    int wid = threadIdx.x >> 6, lane = threadIdx.x & 63;
    int row = blockIdx.x * 4 + wid;
    if (row >= N) return;
    const float4* p = reinterpret_cast<const float4*>(emb + (size_t)row * D);
    float s = 0.f;
    for (int c = lane; c * 4 < D; c += 64) {
        float4 v = p[c];
        s += v.x * v.x + v.y * v.y + v.z * v.z + v.w * v.w;
    }
    s = waveReduceSum(s);
    if (lane == 0) {
        inv_norm[row] = 1.0f / fmaxf(sqrtf(s), 1e-12f);
        atomicAdd(&counts[y[row]], 1);
    }
}

// --- K2: exclusive scan of counts ---
__global__ void k_scan(const int* __restrict__ counts, int* __restrict__ offsets, int C) {
    __shared__ int sc[256];
    int tid = threadIdx.x;
    int v = (tid < C) ? counts[tid] : 0;
    sc[tid] = v;
    __syncthreads();
    for (int off = 1; off < 256; off <<= 1) {
        int t = (tid >= off) ? sc[tid - off] : 0;
        __syncthreads();
        sc[tid] += t;
        __syncthreads();
    }
    if (tid < C) offsets[tid] = sc[tid] - v;
}

// --- K3: scatter member lists ---
__global__ void k_scatter(const int* __restrict__ y, const int* __restrict__ offsets,
                          int* __restrict__ cursor, int* __restrict__ members, int N) {
    int i = blockIdx.x * 256 + threadIdx.x;
    if (i < N) {
        int c = y[i];
        int pos = atomicAdd(&cursor[c], 1);
        members[offsets[c] + pos] = i;
    }
}

// --- K4: per-class sums -> csum_bf16 + normsq + colscale (block per class) ---
__global__ void k_centroid(const float* __restrict__ emb, const float* __restrict__ inv_norm,
                           const int* __restrict__ members, const int* __restrict__ offsets,
                           const int* __restrict__ counts, const float* __restrict__ wptr,
                           unsigned short* __restrict__ csum_bf, float* __restrict__ normsq,
                           float* __restrict__ colscale, int D) {
    __shared__ float lds[4 * 512];
    __shared__ float red[256];
    int c = blockIdx.x;
    int tid = threadIdx.x;
    int wid = tid >> 6, lane = tid & 63;
    int cnt = counts[c], off = offsets[c];
    float4 a0 = make_float4(0, 0, 0, 0), a1 = make_float4(0, 0, 0, 0);
    for (int m = wid; m < cnt; m += 4) {
        int row = members[off + m];
        float inv = inv_norm[row];
        const float4* p = reinterpret_cast<const float4*>(emb + (size_t)row * D);
        float4 v = p[lane];
        float4 u = p[lane + 64];
        a0.x += v.x * inv; a0.y += v.y * inv; a0.z += v.z * inv; a0.w += v.w * inv;
        a1.x += u.x * inv; a1.y += u.y * inv; a1.z += u.z * inv; a1.w += u.w * inv;
    }
    reinterpret_cast<float4*>(lds)[wid * 128 + lane] = a0;
    reinterpret_cast<float4*>(lds)[wid * 128 + 64 + lane] = a1;
    __syncthreads();
    float s0 = lds[tid] + lds[512 + tid] + lds[1024 + tid] + lds[1536 + tid];
    float s1 = lds[256 + tid] + lds[512 + 256 + tid] + lds[1024 + 256 + tid] + lds[1536 + 256 + tid];
    csum_bf[(size_t)c * D + tid] = f2bf(s0);
    csum_bf[(size_t)c * D + 256 + tid] = f2bf(s1);
    red[tid] = s0 * s0 + s1 * s1;
    __syncthreads();
    for (int o = 128; o >= 1; o >>= 1) {
        if (tid < o) red[tid] += red[tid + o];
        __syncthreads();
    }
    if (tid == 0) {
        float nsq = red[0];
        normsq[c] = nsq;
        colscale[c] = wptr[0] / fmaxf(sqrtf(nsq), (float)cnt * 1e-8f);
    }
}

// --- K5: MFMA GEMM (e @ csum^T), fused self-logit + exp + per-column partials ---
// BM=64, BN=128, BK=64. 128 threads (2 waves). Wave w: cols w*64..w*64+63.
// LDS sub-tile = 16 lanes x 32 k bf16 (1KB), XOR-swizzled: chunk' = kc ^ ((rr>>1)&3).
#define NBX 256

__global__ __launch_bounds__(128) void k_gemm(
        const float* __restrict__ emb, const float* __restrict__ inv_norm,
        const unsigned short* __restrict__ csum_bf, const int* __restrict__ y,
        const float* __restrict__ colscale, const float* __restrict__ normsq,
        const int* __restrict__ counts,
        const float* __restrict__ wptr, const float* __restrict__ bptr,
        float* __restrict__ logit_self, float* __restrict__ colpart,
        int N, int D, int C) {
    __shared__ unsigned short As[8 * 512];    // 8 KB
    __shared__ unsigned short Bs[16 * 512];   // 16 KB
    __shared__ float colsum[128];

    const int tid = threadIdx.x;
    const int l = tid & 63;
    const int w = tid >> 6;
    const int r0 = blockIdx.x * 64;
    const int c0 = blockIdx.y * 128;

    // A staging precompute: 4 chunks/thread. ch = tid + i*128 -> st=ch>>6, rr=(ch>>2)&15, kc=ch&3
    const float* asrc[4]; float ainvv[4]; unsigned short* adst[4];
#pragma unroll
    for (int i = 0; i < 4; ++i) {
        int ch = tid + i * 128;
        int st = ch >> 6, rr = (ch >> 2) & 15, kc = ch & 3;
        int row = r0 + (st & 3) * 16 + rr;
        asrc[i] = emb + (size_t)row * D + (st >> 2) * 32 + kc * 8;
        ainvv[i] = inv_norm[row];
        adst[i] = As + st * 512 + rr * 32 + ((kc ^ ((rr >> 1) & 3)) * 8);
    }
    // B staging (global_load_lds, pre-swizzled source): wave w -> subtiles w*8..w*8+7
    const unsigned short* bsrc[8]; unsigned short* bdst[8];
#pragma unroll
    for (int i = 0; i < 8; ++i) {
        int st = w * 8 + i;
        int col = c0 + (st & 7) * 16 + (l >> 2);
        int kc = (l & 3) ^ ((l >> 3) & 3);
        bsrc[i] = csum_bf + (size_t)col * D + (st >> 3) * 32 + kc * 8;
        bdst[i] = Bs + st * 512;   // wave-uniform base; HW adds lane*16B
    }
    // fragment read offset (ushort units): rr=l&15, kc=l>>4, swizzled
    const int fro = (l & 15) * 32 + (((l >> 4) ^ ((l >> 1) & 3)) * 8);

    f32x4 acc[4][4];
#pragma unroll
    for (int m = 0; m < 4; ++m)
#pragma unroll
        for (int n = 0; n < 4; ++n) acc[m][n] = (f32x4){0.f, 0.f, 0.f, 0.f};

    const int nkt = D / 64;
    for (int kt = 0; kt < nkt; ++kt) {
#pragma unroll
        for (int i = 0; i < 8; ++i)
            gload_lds16(bsrc[i] + kt * 64, bdst[i]);
#pragma unroll
        for (int i = 0; i < 4; ++i) {
            const float* s = asrc[i] + kt * 64;
            float4 v0 = *reinterpret_cast<const float4*>(s);
            float4 v1 = *reinterpret_cast<const float4*>(s + 4);
            float iv = ainvv[i];
            BF8 t;
            t.u[0] = f2bf(v0.x * iv); t.u[1] = f2bf(v0.y * iv);
            t.u[2] = f2bf(v0.z * iv); t.u[3] = f2bf(v0.w * iv);
            t.u[4] = f2bf(v1.x * iv); t.u[5] = f2bf(v1.y * iv);
            t.u[6] = f2bf(v1.z * iv); t.u[7] = f2bf(v1.w * iv);
            *reinterpret_cast<BF8*>(adst[i]) = t;
        }
        __syncthreads();
#pragma unroll
        for (int h = 0; h < 2; ++h) {
            bf16x8 af[4];
#pragma unroll
            for (int m = 0; m < 4; ++m)
                af[m] = *reinterpret_cast<const bf16x8*>(As + (h * 4 + m) * 512 + fro);
#pragma unroll
            for (int n = 0; n < 4; ++n) {
                bf16x8 bv = *reinterpret_cast<const bf16x8*>(Bs + (h * 8 + w * 4 + n) * 512 + fro);
#pragma unroll
                for (int m = 0; m < 4; ++m)
                    acc[m][n] = __builtin_amdgcn_mfma_f32_16x16x32_bf16(af[m], bv, acc[m][n], 0, 0, 0);
            }
        }
        __syncthreads();
    }

    // epilogue: C/D layout col=lane&15, row=(lane>>4)*4+j
    float bv = bptr[0], wv = wptr[0];
    int lcol = l & 15, lrow4 = (l >> 4) * 4;
    float cs[4], nsq[4], cm1[4]; int cls[4];
#pragma unroll
    for (int n = 0; n < 4; ++n) {
        int c = c0 + w * 64 + n * 16 + lcol;
        cls[n] = c; cs[n] = colscale[c]; nsq[n] = normsq[c];
        cm1[n] = (float)(counts[c] - 1);
    }
    float colacc[4] = {0.f, 0.f, 0.f, 0.f};
#pragma unroll
    for (int m = 0; m < 4; ++m) {
#pragma unroll
        for (int j = 0; j < 4; ++j) {
            int row = r0 + m * 16 + lrow4 + j;
            int yc = y[row];
#pragma unroll
            for (int n = 0; n < 4; ++n) {
                float dot = acc[m][n][j];
                float logit;
                if (yc == cls[n]) {
                    float un2 = fmaxf(nsq[n] - 2.f * dot + 1.f, 0.f);
                    float denom = fmaxf(sqrtf(un2), cm1[n] * 1e-8f);
                    logit = wv * (dot - 1.f) / denom + bv;
                    logit_self[row] = logit;
                } else {
                    logit = dot * cs[n] + bv;
                }
                colacc[n] += __expf(logit);
            }
        }
    }
#pragma unroll
    for (int n = 0; n < 4; ++n) {
        float v = colacc[n];
        v += __shfl_xor(v, 16, 64);
        v += __shfl_xor(v, 32, 64);
        colacc[n] = v;
    }
    if (l < 16) {
#pragma unroll
        for (int n = 0; n < 4; ++n) colsum[w * 64 + n * 16 + l] = colacc[n];
    }
    __syncthreads();
    if (tid < 128)
        colpart[(size_t)(c0 + tid) * NBX + blockIdx.x] = colsum[tid];
}

// --- K6: per-class reduce -> contrib[c] = counts[c]*log(sum) ---
__global__ void k_colreduce(const float* __restrict__ colpart, const int* __restrict__ counts,
                            float* __restrict__ contrib) {
    int c = blockIdx.x, lane = threadIdx.x;  // 64 threads
    float4 v = reinterpret_cast<const float4*>(colpart + (size_t)c * NBX)[lane];
    float s = v.x + v.y + v.z + v.w;
    s = waveReduceSum(s);
    if (lane == 0) contrib[c] = (float)counts[c] * logf(s);
}

// --- K7: finalize ---
__global__ void k_final(const float* __restrict__ contrib, const float* __restrict__ logit_self,
                        float* __restrict__ out, int N) {
    __shared__ float lds[256];
    int tid = threadIdx.x;
    float s = contrib[tid];
    const float4* p4 = reinterpret_cast<const float4*>(logit_self);
    for (int i = tid; i < N / 4; i += 256) {
        float4 v = p4[i];
        s -= v.x + v.y + v.z + v.w;
    }
    lds[tid] = s;
    __syncthreads();
    for (int off = 128; off >= 1; off >>= 1) {
        if (tid < off) lds[tid] += lds[tid + off];
        __syncthreads();
    }
    if (tid == 0) out[0] = lds[0];
}

extern "C" void kernel_launch(void* const* d_in, const int* in_sizes, int n_in,
                              void* d_out, int out_size, void* d_ws, size_t ws_size,
                              hipStream_t stream) {
    const float* emb  = (const float*)d_in[0];
    const int*   y    = (const int*)d_in[1];
    const float* wptr = (const float*)d_in[2];
    const float* bptr = (const float*)d_in[3];
    float* out = (float*)d_out;
    int N = in_sizes[1];
    int D = in_sizes[0] / N;
    const int C = 256;

    float* ws = (float*)d_ws;
    int*   counts     = (int*)ws;                               // C
    int*   cursor     = counts + C;                             // C
    int*   offsets    = cursor + C;                             // C
    float* inv_norm   = (float*)(offsets + C);                  // N
    float* logit_self = inv_norm + N;                           // N
    int*   members    = (int*)(logit_self + N);                 // N
    float* colscale   = (float*)(members + N);                  // C
    float* normsq     = colscale + C;                           // C
    float* contrib    = normsq + C;                             // C
    unsigned short* csum_bf = (unsigned short*)(contrib + C);   // C*D ushorts
    float* colpart    = (float*)(csum_bf + (size_t)C * D);      // C*NBX

    (void)hipMemsetAsync(counts, 0, 2 * C * sizeof(int), stream);

    k_norms   <<<(N + 3) / 4, 256, 0, stream>>>(emb, y, inv_norm, counts, N, D);
    k_scan    <<<1, 256, 0, stream>>>(counts, offsets, C);
    k_scatter <<<(N + 255) / 256, 256, 0, stream>>>(y, offsets, cursor, members, N);
    k_centroid<<<C, 256, 0, stream>>>(emb, inv_norm, members, offsets, counts, wptr,
                                      csum_bf, normsq, colscale, D);
    dim3 grid(N / 64, C / 128);
    k_gemm    <<<grid, 128, 0, stream>>>(emb, inv_norm, csum_bf, y, colscale, normsq,
                                         counts, wptr, bptr, logit_self, colpart, N, D, C);
    k_colreduce<<<C, 64, 0, stream>>>(colpart, counts, contrib);
    k_final   <<<1, 256, 0, stream>>>(contrib, logit_self, out, N);
}